// Round 3
// baseline (862.183 us; speedup 1.0000x reference)
//
#include <hip/hip_runtime.h>

#define BATCH 16
#define NN 512   // n  (j index, "nxt" side; rows of X)
#define MM 512   // m  (i index, "cur" side; cols of X)
#define DD 128
#define QP_ITERS 20
#define NBLK (BATCH * 16)   // 256 blocks, 1 per CU

// ---------------------------------------------------------------------------
// row_norms: rc[b*512+p] = ||nc[b,p]||^2 + ||ec[b,p]||^2
//            rn[b*512+p] = ||nn[b,p]||^2 + ||en[b,p]||^2
// ---------------------------------------------------------------------------
__global__ __launch_bounds__(64) void row_norms_kernel(
    const float* __restrict__ nc, const float* __restrict__ ec,
    const float* __restrict__ nn, const float* __restrict__ en,
    float* __restrict__ rc, float* __restrict__ rn)
{
    int row = blockIdx.x;            // b*512 + p
    int t   = threadIdx.x;           // 0..63
    size_t base = (size_t)row * DD;

    float2 a = ((const float2*)(nc + base))[t];
    float2 b = ((const float2*)(ec + base))[t];
    float vc = a.x*a.x + a.y*a.y + b.x*b.x + b.y*b.y;

    float2 c = ((const float2*)(nn + base))[t];
    float2 d = ((const float2*)(en + base))[t];
    float vn = c.x*c.x + c.y*c.y + d.x*d.x + d.y*d.y;

    #pragma unroll
    for (int off = 32; off; off >>= 1) {
        vc += __shfl_down(vc, off);
        vn += __shfl_down(vn, off);
    }
    if (t == 0) { rc[row] = vc; rn[row] = vn; }
}

// ---------------------------------------------------------------------------
// gemm_q: qm[b,j,i] = 0.5*(rc[b,i]+rn[b,j]) - (nc_i . nn_j + ec_i . en_j)
// ---------------------------------------------------------------------------
__global__ __launch_bounds__(256) void gemm_q_kernel(
    const float* __restrict__ nc, const float* __restrict__ ec,
    const float* __restrict__ nn, const float* __restrict__ en,
    const float* __restrict__ rc, const float* __restrict__ rn,
    float* __restrict__ qm, float* __restrict__ sumq, float* __restrict__ sumq2)
{
    int b  = blockIdx.z;
    int it = blockIdx.x;   // i tile (cur), 64 wide
    int jt = blockIdx.y;   // j tile (nxt), 64 wide
    int tid = threadIdx.x;
    int tx = tid & 15, ty = tid >> 4;

    __shared__ float As[64][17];
    __shared__ float Bs[64][17];

    float acc[4][4] = {};

    const float* a0 = nn + ((size_t)b*NN + jt*64) * DD;
    const float* a1 = en + ((size_t)b*NN + jt*64) * DD;
    const float* b0 = nc + ((size_t)b*MM + it*64) * DD;
    const float* b1 = ec + ((size_t)b*MM + it*64) * DD;

    int lrow = tid >> 4;   // 0..15
    int lk   = tid & 15;   // 0..15

    for (int mat = 0; mat < 2; ++mat) {
        const float* ap = mat ? a1 : a0;
        const float* bp = mat ? b1 : b0;
        for (int kc = 0; kc < DD; kc += 16) {
            __syncthreads();
            #pragma unroll
            for (int r = 0; r < 4; ++r) {
                int row = lrow + r*16;
                As[row][lk] = ap[(size_t)row*DD + kc + lk];
                Bs[row][lk] = bp[(size_t)row*DD + kc + lk];
            }
            __syncthreads();
            #pragma unroll
            for (int k = 0; k < 16; ++k) {
                float ar[4], br[4];
                #pragma unroll
                for (int r = 0; r < 4; ++r) ar[r] = As[ty*4 + r][k];
                #pragma unroll
                for (int c = 0; c < 4; ++c) br[c] = Bs[tx*4 + c][k];
                #pragma unroll
                for (int r = 0; r < 4; ++r)
                    #pragma unroll
                    for (int c = 0; c < 4; ++c)
                        acc[r][c] += ar[r] * br[c];
            }
        }
    }

    float qs = 0.f, q2s = 0.f;
    #pragma unroll
    for (int r = 0; r < 4; ++r) {
        int j = jt*64 + ty*4 + r;
        float rnj = rn[b*NN + j];
        float4 o;
        float v;
        int i0 = it*64 + tx*4;
        v = 0.5f*(rc[b*MM + i0 + 0] + rnj) - acc[r][0]; o.x = v; qs += v; q2s += v*v;
        v = 0.5f*(rc[b*MM + i0 + 1] + rnj) - acc[r][1]; o.y = v; qs += v; q2s += v*v;
        v = 0.5f*(rc[b*MM + i0 + 2] + rnj) - acc[r][2]; o.z = v; qs += v; q2s += v*v;
        v = 0.5f*(rc[b*MM + i0 + 3] + rnj) - acc[r][3]; o.w = v; qs += v; q2s += v*v;
        *(float4*)(qm + ((size_t)b*NN + j)*MM + i0) = o;
    }

    #pragma unroll
    for (int off = 32; off; off >>= 1) {
        qs  += __shfl_down(qs,  off);
        q2s += __shfl_down(q2s, off);
    }
    __shared__ float red[8];
    int wid = tid >> 6, lane = tid & 63;
    if (lane == 0) { red[wid] = qs; red[4 + wid] = q2s; }
    __syncthreads();
    if (tid == 0) {
        atomicAdd(&sumq[b],  red[0] + red[1] + red[2] + red[3]);
        atomicAdd(&sumq2[b], red[4] + red[5] + red[6] + red[7]);
    }
}

// ---------------------------------------------------------------------------
__global__ __launch_bounds__(1024) void zero_ws_kernel(float* __restrict__ z, int n)
{
    int idx = blockIdx.x * blockDim.x + threadIdx.x;
    if (idx < n) z[idx] = 0.f;
}

__global__ void init_scalars_kernel(const float* __restrict__ sumq,
                                    const float* __restrict__ sumq2,
                                    float* __restrict__ lrbuf, float* __restrict__ s1buf)
{
    int b = threadIdx.x;
    if (b < BATCH) {
        lrbuf[b] = 0.5f / (sumq2[b] + 1e-8f);
        s1buf[b] = sumq[b] * (1.0f / (float)MM);   // s1 = sum(qm)/m  (X0 = 1/m)
    }
}

// ---------------------------------------------------------------------------
// hand-rolled two-level grid barrier (AGENT-scope atomics, no cache flush).
// bar[0..15] = group counters, bar[16] = global counter, bar[17] = epoch.
// e must be monotonically increasing (iteration number).
// ---------------------------------------------------------------------------
__device__ __forceinline__ void grid_barrier(unsigned* bar, unsigned e)
{
    __syncthreads();
    if (threadIdx.x == 0) {
        unsigned grp = blockIdx.x >> 4;
        unsigned o = __hip_atomic_fetch_add(&bar[grp], 1u, __ATOMIC_ACQ_REL,
                                            __HIP_MEMORY_SCOPE_AGENT);
        if (o == 15u) {
            unsigned o2 = __hip_atomic_fetch_add(&bar[16], 1u, __ATOMIC_ACQ_REL,
                                                 __HIP_MEMORY_SCOPE_AGENT);
            if (o2 == 15u) {
                // last arriver: reset counters, then publish epoch (release)
                #pragma unroll
                for (int i = 0; i < 16; ++i)
                    __hip_atomic_store(&bar[i], 0u, __ATOMIC_RELAXED,
                                       __HIP_MEMORY_SCOPE_AGENT);
                __hip_atomic_store(&bar[16], 0u, __ATOMIC_RELAXED,
                                   __HIP_MEMORY_SCOPE_AGENT);
                __hip_atomic_store(&bar[17], e, __ATOMIC_RELEASE,
                                   __HIP_MEMORY_SCOPE_AGENT);
            } else {
                while (__hip_atomic_load(&bar[17], __ATOMIC_ACQUIRE,
                                         __HIP_MEMORY_SCOPE_AGENT) < e)
                    __builtin_amdgcn_s_sleep(4);
            }
        } else {
            while (__hip_atomic_load(&bar[17], __ATOMIC_ACQUIRE,
                                     __HIP_MEMORY_SCOPE_AGENT) < e)
                __builtin_amdgcn_s_sleep(4);
        }
    }
    __syncthreads();
}

// ---------------------------------------------------------------------------
// qp_iter_kernel v2: persistent 20-iteration PGD solve.
// 256 blocks x 1024 threads, qm and X register-resident (16 elems/thread,
// strided columns i = cseg + 32k). Per iteration:
//   - (t>1) stage colsum/colq of prev iter from coherent point into LDS
//     (1 AGENT-scope load/thread), compute f + s block-locally
//   - grad step + clip + row-normalize (shfl, rows intra-half-wave)
//   - fused column partial pass: pair-reduce rows via shfl_xor(32), one
//     LDS write+read pass for BOTH colsum(x) and colsum(q*x), then one
//     device-scope atomicAdd per thread into per-iteration slots
//   - one hand-rolled grid barrier
// ---------------------------------------------------------------------------
__global__ __launch_bounds__(1024, 4) void qp_iter_kernel(
    const float* __restrict__ qm, const float* __restrict__ lrbuf,
    const float* __restrict__ s1buf, float* __restrict__ cbufS,
    float* __restrict__ cbufQ, unsigned* __restrict__ bar,
    float* __restrict__ out)
{
    __shared__ float lds[32 * 512];          // 64 KB
    float* stage = lds;                      // [1024]: 0..511 f, 512..1023 colq
    float* wred  = lds + 1024;               // [16] wave partials for s
    float* sval  = lds + 1040;               // [1]

    int tid   = threadIdx.x;
    int blk   = blockIdx.x;
    int b     = blk >> 4;            // batch
    int g     = blk & 15;            // row-group: rows g*32..g*32+31
    int w     = tid >> 6;            // wave 0..15
    int lane  = tid & 63;
    int r_loc = tid >> 5;            // 0..31 local row
    int cseg  = tid & 31;            // owns cols cseg + 32k
    int j     = g * 32 + r_loc;

    const float lr = lrbuf[b];
    size_t rowbase = ((size_t)b * NN + j) * MM;

    float q[16], x[16], fk[16];
    #pragma unroll
    for (int k = 0; k < 16; ++k) q[k] = qm[rowbase + cseg + 32*k];

    const float inv_m = 1.0f / (float)MM;
    #pragma unroll
    for (int k = 0; k < 16; ++k) { x[k] = inv_m; fk[k] = 1.0f; }

    float s = s1buf[b];

    for (int t = 1; t <= QP_ITERS; ++t) {
        if (t > 1) {
            // ---- stage prev iteration's colsum/colq; compute f and s ----
            const float* csp = cbufS + (size_t)(t - 2) * (BATCH * MM) + b * MM;
            const float* cqp = cbufQ + (size_t)(t - 2) * (BATCH * MM) + b * MM;
            if (tid < 512) {
                float cs = __hip_atomic_load((float*)(csp + tid),
                                             __ATOMIC_RELAXED,
                                             __HIP_MEMORY_SCOPE_AGENT);
                stage[tid] = fminf(1.0f, 2.0f / (cs + 1e-8f));
            } else {
                float cq = __hip_atomic_load((float*)(cqp + (tid - 512)),
                                             __ATOMIC_RELAXED,
                                             __HIP_MEMORY_SCOPE_AGENT);
                stage[tid] = cq;
            }
            __syncthreads();
            float v = (tid < 512) ? stage[tid] * stage[512 + tid] : 0.f;
            #pragma unroll
            for (int m = 32; m; m >>= 1) v += __shfl_xor(v, m);
            if (lane == 0) wred[w] = v;
            #pragma unroll
            for (int k = 0; k < 16; ++k) fk[k] = stage[cseg + 32*k];
            __syncthreads();
            if (tid == 0) {
                float sacc = 0.f;
                #pragma unroll
                for (int i = 0; i < 16; ++i) sacc += wred[i];
                sval[0] = sacc;
            }
            __syncthreads();
            s = sval[0];
        }

        // ---- gradient step + clip + row normalize ----
        float c = 2.0f * lr * s;
        float rp = 0.f;
        #pragma unroll
        for (int k = 0; k < 16; ++k) {
            float v = x[k] * fk[k] - c * q[k];
            v = fminf(fmaxf(v, 0.f), 1.f);
            x[k] = v;
            rp += v;
        }
        #pragma unroll
        for (int m = 16; m; m >>= 1) rp += __shfl_xor(rp, m);
        float inv = 1.0f / (rp + 1e-8f);
        #pragma unroll
        for (int k = 0; k < 16; ++k) x[k] *= inv;

        // ---- fused column partial pass ----
        __syncthreads();   // protect stage region before overwrite
        #pragma unroll
        for (int k = 0; k < 16; ++k) {
            float qx = q[k] * x[k];
            float px = x[k] + __shfl_xor(x[k], 32);   // row-pair sum
            float pq = qx   + __shfl_xor(qx,   32);
            int col = cseg + 32*k;
            if (lane < 32) lds[w * 512 + col]        = px;   // x partials
            else           lds[8192 + w * 512 + col] = pq;   // qx partials
        }
        __syncthreads();
        {
            int arr = tid >> 9;          // 0 => colsum(x), 1 => colsum(qx)
            int col = tid & 511;
            const float* basep = lds + arr * 8192 + col;
            float acc = 0.f;
            #pragma unroll
            for (int w2 = 0; w2 < 16; ++w2) acc += basep[w2 * 512];
            float* dst = (arr ? cbufQ : cbufS)
                       + (size_t)(t - 1) * (BATCH * MM) + b * MM + col;
            atomicAdd(dst, acc);
        }

        grid_barrier(bar, (unsigned)t);
    }

    // ---- final lazy column scale from iteration 20's colsum ----
    {
        const float* csp = cbufS + (size_t)(QP_ITERS - 1) * (BATCH * MM) + b * MM;
        if (tid < 512) {
            float cs = __hip_atomic_load((float*)(csp + tid),
                                         __ATOMIC_RELAXED,
                                         __HIP_MEMORY_SCOPE_AGENT);
            stage[tid] = fminf(1.0f, 2.0f / (cs + 1e-8f));
        }
        __syncthreads();
        #pragma unroll
        for (int k = 0; k < 16; ++k)
            out[rowbase + cseg + 32*k] = x[k] * stage[cseg + 32*k];
    }
}

// ---------------------------------------------------------------------------
extern "C" void kernel_launch(void* const* d_in, const int* in_sizes, int n_in,
                              void* d_out, int out_size, void* d_ws, size_t ws_size,
                              hipStream_t stream)
{
    const float* nc = (const float*)d_in[0];  // n_emb_cur (16,512,128)
    const float* ec = (const float*)d_in[1];  // e_emb_cur
    const float* nn = (const float*)d_in[2];  // n_emb_nxt
    const float* en = (const float*)d_in[3];  // e_emb_nxt
    float* out = (float*)d_out;               // (16, 512*512) fp32

    float* ws = (float*)d_ws;
    const size_t QM_FLOATS = (size_t)BATCH * NN * MM;       // 4,194,304

    float* qm    = ws;
    // contiguous zero region: sumq, sumq2, cbufS, cbufQ, barrier words
    float* zreg  = ws + QM_FLOATS;
    float* sumq  = zreg;                                    // 16
    float* sumq2 = zreg + 16;                               // 16
    float* cbufS = zreg + 32;                               // 20*16*512
    float* cbufQ = cbufS + (size_t)QP_ITERS * BATCH * MM;
    unsigned* bar = (unsigned*)(cbufQ + (size_t)QP_ITERS * BATCH * MM);  // 64
    const int ZN = 32 + 2 * QP_ITERS * BATCH * MM + 64;
    float* rc    = zreg + ZN;                               // 8192
    float* rn    = rc + BATCH * MM;                         // 8192
    float* lrbuf = rn + BATCH * NN;                         // 16
    float* s1buf = lrbuf + 16;                              // 16

    zero_ws_kernel<<<(ZN + 1023) / 1024, 1024, 0, stream>>>(zreg, ZN);
    row_norms_kernel<<<BATCH * 512, 64, 0, stream>>>(nc, ec, nn, en, rc, rn);
    gemm_q_kernel<<<dim3(8, 8, BATCH), 256, 0, stream>>>(nc, ec, nn, en, rc, rn,
                                                         qm, sumq, sumq2);
    init_scalars_kernel<<<1, 64, 0, stream>>>(sumq, sumq2, lrbuf, s1buf);

    void* args[] = { (void*)&qm, (void*)&lrbuf, (void*)&s1buf,
                     (void*)&cbufS, (void*)&cbufQ, (void*)&bar, (void*)&out };
    hipLaunchCooperativeKernel((const void*)qp_iter_kernel,
                               dim3(NBLK), dim3(1024),
                               args, 0, stream);
}

// Round 4
// 620.444 us; speedup vs baseline: 1.3896x; 1.3896x over previous
//
#include <hip/hip_runtime.h>

#define BATCH 16
#define NN 512   // n  (j index, "nxt" side; rows of X)
#define MM 512   // m  (i index, "cur" side; cols of X)
#define DD 128
#define QP_ITERS 20
#define NBLK (BATCH * 16)   // 256 blocks, 1 per CU
#define SLOT 1024           // floats per block slot (512 x-partials + 512 qx)

// ---------------------------------------------------------------------------
// row_norms: rc[b*512+p] = ||nc[b,p]||^2 + ||ec[b,p]||^2
//            rn[b*512+p] = ||nn[b,p]||^2 + ||en[b,p]||^2
// ---------------------------------------------------------------------------
__global__ __launch_bounds__(64) void row_norms_kernel(
    const float* __restrict__ nc, const float* __restrict__ ec,
    const float* __restrict__ nn, const float* __restrict__ en,
    float* __restrict__ rc, float* __restrict__ rn)
{
    int row = blockIdx.x;            // b*512 + p
    int t   = threadIdx.x;           // 0..63
    size_t base = (size_t)row * DD;

    float2 a = ((const float2*)(nc + base))[t];
    float2 b = ((const float2*)(ec + base))[t];
    float vc = a.x*a.x + a.y*a.y + b.x*b.x + b.y*b.y;

    float2 c = ((const float2*)(nn + base))[t];
    float2 d = ((const float2*)(en + base))[t];
    float vn = c.x*c.x + c.y*c.y + d.x*d.x + d.y*d.y;

    #pragma unroll
    for (int off = 32; off; off >>= 1) {
        vc += __shfl_down(vc, off);
        vn += __shfl_down(vn, off);
    }
    if (t == 0) { rc[row] = vc; rn[row] = vn; }
}

// ---------------------------------------------------------------------------
// gemm_q: qm[b,j,i] = 0.5*(rc[b,i]+rn[b,j]) - (nc_i . nn_j + ec_i . en_j)
// ---------------------------------------------------------------------------
__global__ __launch_bounds__(256) void gemm_q_kernel(
    const float* __restrict__ nc, const float* __restrict__ ec,
    const float* __restrict__ nn, const float* __restrict__ en,
    const float* __restrict__ rc, const float* __restrict__ rn,
    float* __restrict__ qm, float* __restrict__ sumq, float* __restrict__ sumq2)
{
    int b  = blockIdx.z;
    int it = blockIdx.x;   // i tile (cur), 64 wide
    int jt = blockIdx.y;   // j tile (nxt), 64 wide
    int tid = threadIdx.x;
    int tx = tid & 15, ty = tid >> 4;

    __shared__ float As[64][17];
    __shared__ float Bs[64][17];

    float acc[4][4] = {};

    const float* a0 = nn + ((size_t)b*NN + jt*64) * DD;
    const float* a1 = en + ((size_t)b*NN + jt*64) * DD;
    const float* b0 = nc + ((size_t)b*MM + it*64) * DD;
    const float* b1 = ec + ((size_t)b*MM + it*64) * DD;

    int lrow = tid >> 4;   // 0..15
    int lk   = tid & 15;   // 0..15

    for (int mat = 0; mat < 2; ++mat) {
        const float* ap = mat ? a1 : a0;
        const float* bp = mat ? b1 : b0;
        for (int kc = 0; kc < DD; kc += 16) {
            __syncthreads();
            #pragma unroll
            for (int r = 0; r < 4; ++r) {
                int row = lrow + r*16;
                As[row][lk] = ap[(size_t)row*DD + kc + lk];
                Bs[row][lk] = bp[(size_t)row*DD + kc + lk];
            }
            __syncthreads();
            #pragma unroll
            for (int k = 0; k < 16; ++k) {
                float ar[4], br[4];
                #pragma unroll
                for (int r = 0; r < 4; ++r) ar[r] = As[ty*4 + r][k];
                #pragma unroll
                for (int c = 0; c < 4; ++c) br[c] = Bs[tx*4 + c][k];
                #pragma unroll
                for (int r = 0; r < 4; ++r)
                    #pragma unroll
                    for (int c = 0; c < 4; ++c)
                        acc[r][c] += ar[r] * br[c];
            }
        }
    }

    float qs = 0.f, q2s = 0.f;
    #pragma unroll
    for (int r = 0; r < 4; ++r) {
        int j = jt*64 + ty*4 + r;
        float rnj = rn[b*NN + j];
        float4 o;
        float v;
        int i0 = it*64 + tx*4;
        v = 0.5f*(rc[b*MM + i0 + 0] + rnj) - acc[r][0]; o.x = v; qs += v; q2s += v*v;
        v = 0.5f*(rc[b*MM + i0 + 1] + rnj) - acc[r][1]; o.y = v; qs += v; q2s += v*v;
        v = 0.5f*(rc[b*MM + i0 + 2] + rnj) - acc[r][2]; o.z = v; qs += v; q2s += v*v;
        v = 0.5f*(rc[b*MM + i0 + 3] + rnj) - acc[r][3]; o.w = v; qs += v; q2s += v*v;
        *(float4*)(qm + ((size_t)b*NN + j)*MM + i0) = o;
    }

    #pragma unroll
    for (int off = 32; off; off >>= 1) {
        qs  += __shfl_down(qs,  off);
        q2s += __shfl_down(q2s, off);
    }
    __shared__ float red[8];
    int wid = tid >> 6, lane = tid & 63;
    if (lane == 0) { red[wid] = qs; red[4 + wid] = q2s; }
    __syncthreads();
    if (tid == 0) {
        atomicAdd(&sumq[b],  red[0] + red[1] + red[2] + red[3]);
        atomicAdd(&sumq2[b], red[4] + red[5] + red[6] + red[7]);
    }
}

// ---------------------------------------------------------------------------
__global__ __launch_bounds__(256) void zero_ws_kernel(float* __restrict__ z, int n)
{
    int idx = blockIdx.x * blockDim.x + threadIdx.x;
    if (idx < n) z[idx] = 0.f;
}

__global__ void init_scalars_kernel(const float* __restrict__ sumq,
                                    const float* __restrict__ sumq2,
                                    float* __restrict__ lrbuf, float* __restrict__ s1buf)
{
    int b = threadIdx.x;
    if (b < BATCH) {
        lrbuf[b] = 0.5f / (sumq2[b] + 1e-8f);
        s1buf[b] = sumq[b] * (1.0f / (float)MM);   // s1 = sum(qm)/m  (X0 = 1/m)
    }
}

// ---------------------------------------------------------------------------
// single-counter grid barrier. bar[0]=counter, bar[1]=epoch (monotone).
// ---------------------------------------------------------------------------
__device__ __forceinline__ void grid_barrier(unsigned* bar, unsigned e)
{
    __syncthreads();
    if (threadIdx.x == 0) {
        unsigned o = __hip_atomic_fetch_add(&bar[0], 1u, __ATOMIC_ACQ_REL,
                                            __HIP_MEMORY_SCOPE_AGENT);
        if (o == (unsigned)(NBLK - 1)) {
            __hip_atomic_store(&bar[0], 0u, __ATOMIC_RELAXED,
                               __HIP_MEMORY_SCOPE_AGENT);
            __hip_atomic_store(&bar[1], e, __ATOMIC_RELEASE,
                               __HIP_MEMORY_SCOPE_AGENT);
        } else {
            while (__hip_atomic_load(&bar[1], __ATOMIC_ACQUIRE,
                                     __HIP_MEMORY_SCOPE_AGENT) < e)
                __builtin_amdgcn_s_sleep(1);
        }
    }
    __syncthreads();
}

// ---------------------------------------------------------------------------
// qp_iter_kernel v3: persistent 20-iteration PGD solve.
// 256 blocks x 1024 threads, qm and X register-resident (16 elems/thread,
// strided columns i = cseg + 32k). ZERO contended atomics: each block writes
// its 512+512 column partials to a PRIVATE slot (relaxed agent stores,
// double-buffered by iteration parity), one single-counter barrier, then each
// block re-reads the 16 slots of its batch (coalesced agent loads) and
// reduces f + s locally.
// ---------------------------------------------------------------------------
__global__ __launch_bounds__(1024, 4) void qp_iter_kernel(
    const float* __restrict__ qm, const float* __restrict__ lrbuf,
    const float* __restrict__ s1buf, float* __restrict__ part,
    unsigned* __restrict__ bar, float* __restrict__ out)
{
    __shared__ float lds[32 * 512];          // 64 KB
    float* stage = lds;                      // [1024]: 0..511 f, 512..1023 colq
    float* wred  = lds + 1024;               // [16] wave partials for s
    float* sval  = lds + 1040;               // [1]

    int tid   = threadIdx.x;
    int blk   = blockIdx.x;
    int b     = blk >> 4;            // batch
    int g     = blk & 15;            // row-group: rows g*32..g*32+31
    int w     = tid >> 6;            // wave 0..15
    int lane  = tid & 63;
    int r_loc = tid >> 5;            // 0..31 local row
    int cseg  = tid & 31;            // owns cols cseg + 32k
    int j     = g * 32 + r_loc;

    const float lr = lrbuf[b];
    size_t rowbase = ((size_t)b * NN + j) * MM;

    float q[16], x[16], fk[16];
    #pragma unroll
    for (int k = 0; k < 16; ++k) q[k] = qm[rowbase + cseg + 32*k];

    const float inv_m = 1.0f / (float)MM;
    #pragma unroll
    for (int k = 0; k < 16; ++k) { x[k] = inv_m; fk[k] = 1.0f; }

    float s = s1buf[b];

    for (int t = 1; t <= QP_ITERS; ++t) {
        if (t > 1) {
            // ---- gather prev iteration's partials; compute f and colq ----
            const float* p = part + (size_t)((t - 1) & 1) * (NBLK * SLOT)
                           + (size_t)b * (16 * SLOT) + tid;
            float acc = 0.f;
            #pragma unroll
            for (int g2 = 0; g2 < 16; ++g2)
                acc += __hip_atomic_load((float*)(p + g2 * SLOT),
                                         __ATOMIC_RELAXED,
                                         __HIP_MEMORY_SCOPE_AGENT);
            if (tid < 512) stage[tid] = fminf(1.0f, 2.0f / (acc + 1e-8f)); // f
            else           stage[tid] = acc;                               // colq
            __syncthreads();
            float v = (tid < 512) ? stage[tid] * stage[512 + tid] : 0.f;
            #pragma unroll
            for (int m = 32; m; m >>= 1) v += __shfl_xor(v, m);
            if (lane == 0) wred[w] = v;
            #pragma unroll
            for (int k = 0; k < 16; ++k) fk[k] = stage[cseg + 32*k];
            __syncthreads();
            if (tid == 0) {
                float sacc = 0.f;
                #pragma unroll
                for (int i = 0; i < 16; ++i) sacc += wred[i];
                sval[0] = sacc;
            }
            __syncthreads();
            s = sval[0];
        }

        // ---- gradient step + clip + row normalize ----
        float c = 2.0f * lr * s;
        float rp = 0.f;
        #pragma unroll
        for (int k = 0; k < 16; ++k) {
            float v = x[k] * fk[k] - c * q[k];
            v = fminf(fmaxf(v, 0.f), 1.f);
            x[k] = v;
            rp += v;
        }
        #pragma unroll
        for (int m = 16; m; m >>= 1) rp += __shfl_xor(rp, m);
        float inv = 1.0f / (rp + 1e-8f);
        #pragma unroll
        for (int k = 0; k < 16; ++k) x[k] *= inv;

        // ---- fused column partial pass ----
        __syncthreads();   // protect stage region before overwrite
        #pragma unroll
        for (int k = 0; k < 16; ++k) {
            float qx = q[k] * x[k];
            float px = x[k] + __shfl_xor(x[k], 32);   // row-pair sum
            float pq = qx   + __shfl_xor(qx,   32);
            int col = cseg + 32*k;
            if (lane < 32) lds[w * 512 + col]        = px;   // x partials
            else           lds[8192 + w * 512 + col] = pq;   // qx partials
        }
        __syncthreads();
        {
            int arr = tid >> 9;          // 0 => colsum(x), 1 => colsum(qx)
            int col = tid & 511;
            const float* basep = lds + arr * 8192 + col;
            float acc = 0.f;
            #pragma unroll
            for (int w2 = 0; w2 < 16; ++w2) acc += basep[w2 * 512];
            // private slot, no contention
            float* dst = part + (size_t)(t & 1) * (NBLK * SLOT)
                       + (size_t)blk * SLOT + tid;
            __hip_atomic_store(dst, acc, __ATOMIC_RELAXED,
                               __HIP_MEMORY_SCOPE_AGENT);
        }

        grid_barrier(bar, (unsigned)t);
    }

    // ---- final lazy column scale from iteration 20's colsum ----
    {
        const float* p = part + (size_t)(QP_ITERS & 1) * (NBLK * SLOT)
                       + (size_t)b * (16 * SLOT) + tid;   // tid<512: x-partials
        if (tid < 512) {
            float acc = 0.f;
            #pragma unroll
            for (int g2 = 0; g2 < 16; ++g2)
                acc += __hip_atomic_load((float*)(p + g2 * SLOT),
                                         __ATOMIC_RELAXED,
                                         __HIP_MEMORY_SCOPE_AGENT);
            stage[tid] = fminf(1.0f, 2.0f / (acc + 1e-8f));
        }
        __syncthreads();
        #pragma unroll
        for (int k = 0; k < 16; ++k)
            out[rowbase + cseg + 32*k] = x[k] * stage[cseg + 32*k];
    }
}

// ---------------------------------------------------------------------------
extern "C" void kernel_launch(void* const* d_in, const int* in_sizes, int n_in,
                              void* d_out, int out_size, void* d_ws, size_t ws_size,
                              hipStream_t stream)
{
    const float* nc = (const float*)d_in[0];  // n_emb_cur (16,512,128)
    const float* ec = (const float*)d_in[1];  // e_emb_cur
    const float* nn = (const float*)d_in[2];  // n_emb_nxt
    const float* en = (const float*)d_in[3];  // e_emb_nxt
    float* out = (float*)d_out;               // (16, 512*512) fp32

    float* ws = (float*)d_ws;
    const size_t QM_FLOATS = (size_t)BATCH * NN * MM;       // 4,194,304

    float* qm   = ws;
    float* part = ws + QM_FLOATS;                           // 2*NBLK*1024 floats
    float* zreg = part + (size_t)2 * NBLK * SLOT;
    float* sumq  = zreg;                                    // 16
    float* sumq2 = zreg + 16;                               // 16
    unsigned* bar = (unsigned*)(zreg + 32);                 // 64 words
    const int ZN = 96;
    float* rc    = zreg + 128;                              // 8192
    float* rn    = rc + BATCH * MM;                         // 8192
    float* lrbuf = rn + BATCH * NN;                         // 16
    float* s1buf = lrbuf + 16;                              // 16

    zero_ws_kernel<<<1, 256, 0, stream>>>(zreg, ZN);
    row_norms_kernel<<<BATCH * 512, 64, 0, stream>>>(nc, ec, nn, en, rc, rn);
    gemm_q_kernel<<<dim3(8, 8, BATCH), 256, 0, stream>>>(nc, ec, nn, en, rc, rn,
                                                         qm, sumq, sumq2);
    init_scalars_kernel<<<1, 64, 0, stream>>>(sumq, sumq2, lrbuf, s1buf);

    void* args[] = { (void*)&qm, (void*)&lrbuf, (void*)&s1buf,
                     (void*)&part, (void*)&bar, (void*)&out };
    hipLaunchCooperativeKernel((const void*)qp_iter_kernel,
                               dim3(NBLK), dim3(1024),
                               args, 0, stream);
}

// Round 5
// 395.566 us; speedup vs baseline: 2.1796x; 1.5685x over previous
//
#include <hip/hip_runtime.h>

#define BATCH 16
#define NN 512   // n  (j index, "nxt" side; rows of X)
#define MM 512   // m  (i index, "cur" side; cols of X)
#define DD 128
#define QP_ITERS 20
#define NBLK (BATCH * 16)   // 256 blocks, 1 per CU
#define SLOT 1024           // floats per block slot (512 x-partials + 512 qx)

// ---------------------------------------------------------------------------
// row_norms: rc[b*512+p] = ||nc[b,p]||^2 + ||ec[b,p]||^2
//            rn[b*512+p] = ||nn[b,p]||^2 + ||en[b,p]||^2
// ---------------------------------------------------------------------------
__global__ __launch_bounds__(64) void row_norms_kernel(
    const float* __restrict__ nc, const float* __restrict__ ec,
    const float* __restrict__ nn, const float* __restrict__ en,
    float* __restrict__ rc, float* __restrict__ rn)
{
    int row = blockIdx.x;            // b*512 + p
    int t   = threadIdx.x;           // 0..63
    size_t base = (size_t)row * DD;

    float2 a = ((const float2*)(nc + base))[t];
    float2 b = ((const float2*)(ec + base))[t];
    float vc = a.x*a.x + a.y*a.y + b.x*b.x + b.y*b.y;

    float2 c = ((const float2*)(nn + base))[t];
    float2 d = ((const float2*)(en + base))[t];
    float vn = c.x*c.x + c.y*c.y + d.x*d.x + d.y*d.y;

    #pragma unroll
    for (int off = 32; off; off >>= 1) {
        vc += __shfl_down(vc, off);
        vn += __shfl_down(vn, off);
    }
    if (t == 0) { rc[row] = vc; rn[row] = vn; }
}

// ---------------------------------------------------------------------------
// gemm_q: qm[b,j,i] = 0.5*(rc[b,i]+rn[b,j]) - (nc_i . nn_j + ec_i . en_j)
// ---------------------------------------------------------------------------
__global__ __launch_bounds__(256) void gemm_q_kernel(
    const float* __restrict__ nc, const float* __restrict__ ec,
    const float* __restrict__ nn, const float* __restrict__ en,
    const float* __restrict__ rc, const float* __restrict__ rn,
    float* __restrict__ qm, float* __restrict__ sumq, float* __restrict__ sumq2)
{
    int b  = blockIdx.z;
    int it = blockIdx.x;   // i tile (cur), 64 wide
    int jt = blockIdx.y;   // j tile (nxt), 64 wide
    int tid = threadIdx.x;
    int tx = tid & 15, ty = tid >> 4;

    __shared__ float As[64][17];
    __shared__ float Bs[64][17];

    float acc[4][4] = {};

    const float* a0 = nn + ((size_t)b*NN + jt*64) * DD;
    const float* a1 = en + ((size_t)b*NN + jt*64) * DD;
    const float* b0 = nc + ((size_t)b*MM + it*64) * DD;
    const float* b1 = ec + ((size_t)b*MM + it*64) * DD;

    int lrow = tid >> 4;   // 0..15
    int lk   = tid & 15;   // 0..15

    for (int mat = 0; mat < 2; ++mat) {
        const float* ap = mat ? a1 : a0;
        const float* bp = mat ? b1 : b0;
        for (int kc = 0; kc < DD; kc += 16) {
            __syncthreads();
            #pragma unroll
            for (int r = 0; r < 4; ++r) {
                int row = lrow + r*16;
                As[row][lk] = ap[(size_t)row*DD + kc + lk];
                Bs[row][lk] = bp[(size_t)row*DD + kc + lk];
            }
            __syncthreads();
            #pragma unroll
            for (int k = 0; k < 16; ++k) {
                float ar[4], br[4];
                #pragma unroll
                for (int r = 0; r < 4; ++r) ar[r] = As[ty*4 + r][k];
                #pragma unroll
                for (int c = 0; c < 4; ++c) br[c] = Bs[tx*4 + c][k];
                #pragma unroll
                for (int r = 0; r < 4; ++r)
                    #pragma unroll
                    for (int c = 0; c < 4; ++c)
                        acc[r][c] += ar[r] * br[c];
            }
        }
    }

    float qs = 0.f, q2s = 0.f;
    #pragma unroll
    for (int r = 0; r < 4; ++r) {
        int j = jt*64 + ty*4 + r;
        float rnj = rn[b*NN + j];
        float4 o;
        float v;
        int i0 = it*64 + tx*4;
        v = 0.5f*(rc[b*MM + i0 + 0] + rnj) - acc[r][0]; o.x = v; qs += v; q2s += v*v;
        v = 0.5f*(rc[b*MM + i0 + 1] + rnj) - acc[r][1]; o.y = v; qs += v; q2s += v*v;
        v = 0.5f*(rc[b*MM + i0 + 2] + rnj) - acc[r][2]; o.z = v; qs += v; q2s += v*v;
        v = 0.5f*(rc[b*MM + i0 + 3] + rnj) - acc[r][3]; o.w = v; qs += v; q2s += v*v;
        *(float4*)(qm + ((size_t)b*NN + j)*MM + i0) = o;
    }

    #pragma unroll
    for (int off = 32; off; off >>= 1) {
        qs  += __shfl_down(qs,  off);
        q2s += __shfl_down(q2s, off);
    }
    __shared__ float red[8];
    int wid = tid >> 6, lane = tid & 63;
    if (lane == 0) { red[wid] = qs; red[4 + wid] = q2s; }
    __syncthreads();
    if (tid == 0) {
        atomicAdd(&sumq[b],  red[0] + red[1] + red[2] + red[3]);
        atomicAdd(&sumq2[b], red[4] + red[5] + red[6] + red[7]);
    }
}

// ---------------------------------------------------------------------------
__global__ __launch_bounds__(256) void zero_ws_kernel(float* __restrict__ z, int n)
{
    int idx = blockIdx.x * blockDim.x + threadIdx.x;
    if (idx < n) z[idx] = 0.f;
}

__global__ void init_scalars_kernel(const float* __restrict__ sumq,
                                    const float* __restrict__ sumq2,
                                    float* __restrict__ lrbuf, float* __restrict__ s1buf)
{
    int b = threadIdx.x;
    if (b < BATCH) {
        lrbuf[b] = 0.5f / (sumq2[b] + 1e-8f);
        s1buf[b] = sumq[b] * (1.0f / (float)MM);   // s1 = sum(qm)/m  (X0 = 1/m)
    }
}

// ---------------------------------------------------------------------------
// qp_iter_kernel v4: persistent 20-iteration PGD solve.
// 256 blocks x 1024 threads; qm and X register-resident (16 elems/thread,
// strided columns i = cseg + 32k). Synchronization is PER-BATCH and RMW-free:
// block (b,g) release-stores epoch t to its own flag word flags[b*32+g];
// wave 0 polls the batch's 16 flags in parallel (acquire loads + __all).
// Column partials go to private per-block slots (relaxed agent stores,
// parity double-buffered); each block gathers its batch's 16 slots after
// the flag sync and reduces f + s locally.
// ---------------------------------------------------------------------------
__global__ __launch_bounds__(1024, 4) void qp_iter_kernel(
    const float* __restrict__ qm, const float* __restrict__ lrbuf,
    const float* __restrict__ s1buf, float* __restrict__ part,
    unsigned* __restrict__ flags, float* __restrict__ out)
{
    __shared__ float lds[16384 + 32];        // 64 KB partials + wred (disjoint)
    float* stage = lds;                      // [1024]: 0..511 f, 512..1023 colq
    float* wred  = lds + 16384;              // [16] wave partials for s

    int tid   = threadIdx.x;
    int blk   = blockIdx.x;
    int b     = blk >> 4;            // batch
    int g     = blk & 15;            // row-group: rows g*32..g*32+31
    int w     = tid >> 6;            // wave 0..15
    int lane  = tid & 63;
    int r_loc = tid >> 5;            // 0..31 local row
    int cseg  = tid & 31;            // owns cols cseg + 32k
    int j     = g * 32 + r_loc;

    const float lr = lrbuf[b];
    size_t rowbase = ((size_t)b * NN + j) * MM;

    float q[16], x[16], fk[16];
    #pragma unroll
    for (int k = 0; k < 16; ++k) q[k] = qm[rowbase + cseg + 32*k];

    const float inv_m = 1.0f / (float)MM;
    #pragma unroll
    for (int k = 0; k < 16; ++k) { x[k] = inv_m; fk[k] = 1.0f; }

    float s = s1buf[b];
    unsigned* myflag = flags + b * 32 + g;
    unsigned* bflags = flags + b * 32;

    for (int t = 1; t <= QP_ITERS; ++t) {
        if (t > 1) {
            // ---- gather prev iteration's partials (parity (t-1)&1) ----
            const float* p = part + (size_t)((t - 1) & 1) * (NBLK * SLOT)
                           + (size_t)b * (16 * SLOT) + tid;
            float acc = 0.f;
            #pragma unroll
            for (int g2 = 0; g2 < 16; ++g2)
                acc += __hip_atomic_load((float*)(p + g2 * SLOT),
                                         __ATOMIC_RELAXED,
                                         __HIP_MEMORY_SCOPE_AGENT);
            if (tid < 512) stage[tid] = fminf(1.0f, 2.0f / (acc + 1e-8f)); // f
            else           stage[tid] = acc;                               // colq
            __syncthreads();
            float v = (tid < 512) ? stage[tid] * stage[512 + tid] : 0.f;
            #pragma unroll
            for (int m = 32; m; m >>= 1) v += __shfl_xor(v, m);
            if (lane == 0) wred[w] = v;
            #pragma unroll
            for (int k = 0; k < 16; ++k) fk[k] = stage[cseg + 32*k];
            __syncthreads();
            float sacc = 0.f;
            #pragma unroll
            for (int i = 0; i < 16; ++i) sacc += wred[i];   // LDS broadcast
            s = sacc;
        }

        // ---- gradient step + clip + row normalize ----
        float c = 2.0f * lr * s;
        float rp = 0.f;
        #pragma unroll
        for (int k = 0; k < 16; ++k) {
            float v = x[k] * fk[k] - c * q[k];
            v = fminf(fmaxf(v, 0.f), 1.f);
            x[k] = v;
            rp += v;
        }
        #pragma unroll
        for (int m = 16; m; m >>= 1) rp += __shfl_xor(rp, m);
        float inv = 1.0f / (rp + 1e-8f);
        #pragma unroll
        for (int k = 0; k < 16; ++k) x[k] *= inv;

        // ---- column partial pass (wred is disjoint; no extra barrier) ----
        __syncthreads();   // all threads done reading stage before overwrite
        #pragma unroll
        for (int k = 0; k < 16; ++k) {
            float qx = q[k] * x[k];
            float px = x[k] + __shfl_xor(x[k], 32);   // row-pair sum
            float pq = qx   + __shfl_xor(qx,   32);
            int col = cseg + 32*k;
            if (lane < 32) lds[w * 512 + col]        = px;   // x partials
            else           lds[8192 + w * 512 + col] = pq;   // qx partials
        }
        __syncthreads();
        {
            int arr = tid >> 9;          // 0 => colsum(x), 1 => colsum(qx)
            int col = tid & 511;
            const float* basep = lds + arr * 8192 + col;
            float acc = 0.f;
            #pragma unroll
            for (int w2 = 0; w2 < 16; ++w2) acc += basep[w2 * 512];
            float* dst = part + (size_t)(t & 1) * (NBLK * SLOT)
                       + (size_t)blk * SLOT + tid;
            __hip_atomic_store(dst, acc, __ATOMIC_RELAXED,
                               __HIP_MEMORY_SCOPE_AGENT);
        }

        // ---- per-batch flag sync (no RMW) ----
        __syncthreads();   // drain every thread's partial store (vmcnt 0)
        if (tid == 0)
            __hip_atomic_store(myflag, (unsigned)t, __ATOMIC_RELEASE,
                               __HIP_MEMORY_SCOPE_AGENT);
        if (w == 0) {
            for (;;) {
                unsigned v = (lane < 16)
                    ? __hip_atomic_load(bflags + lane, __ATOMIC_ACQUIRE,
                                        __HIP_MEMORY_SCOPE_AGENT)
                    : (unsigned)t;
                if (__all(v >= (unsigned)t)) break;
            }
        }
        __syncthreads();
    }

    // ---- final lazy column scale from iteration 20's colsum ----
    {
        const float* p = part + (size_t)(QP_ITERS & 1) * (NBLK * SLOT)
                       + (size_t)b * (16 * SLOT) + tid;   // tid<512: x-partials
        if (tid < 512) {
            float acc = 0.f;
            #pragma unroll
            for (int g2 = 0; g2 < 16; ++g2)
                acc += __hip_atomic_load((float*)(p + g2 * SLOT),
                                         __ATOMIC_RELAXED,
                                         __HIP_MEMORY_SCOPE_AGENT);
            stage[tid] = fminf(1.0f, 2.0f / (acc + 1e-8f));
        }
        __syncthreads();
        #pragma unroll
        for (int k = 0; k < 16; ++k)
            out[rowbase + cseg + 32*k] = x[k] * stage[cseg + 32*k];
    }
}

// ---------------------------------------------------------------------------
extern "C" void kernel_launch(void* const* d_in, const int* in_sizes, int n_in,
                              void* d_out, int out_size, void* d_ws, size_t ws_size,
                              hipStream_t stream)
{
    const float* nc = (const float*)d_in[0];  // n_emb_cur (16,512,128)
    const float* ec = (const float*)d_in[1];  // e_emb_cur
    const float* nn = (const float*)d_in[2];  // n_emb_nxt
    const float* en = (const float*)d_in[3];  // e_emb_nxt
    float* out = (float*)d_out;               // (16, 512*512) fp32

    float* ws = (float*)d_ws;
    const size_t QM_FLOATS = (size_t)BATCH * NN * MM;       // 4,194,304

    float* qm   = ws;
    float* part = ws + QM_FLOATS;                           // 2*NBLK*1024 floats
    // contiguous zero region: sumq, sumq2, flags
    float* zreg  = part + (size_t)2 * NBLK * SLOT;
    float* sumq  = zreg;                                    // 16
    float* sumq2 = zreg + 16;                               // 16
    unsigned* flags = (unsigned*)(zreg + 32);               // 16*32 words
    const int ZN = 32 + BATCH * 32;                         // 544
    float* rc    = zreg + 576;                              // 8192
    float* rn    = rc + BATCH * MM;                         // 8192
    float* lrbuf = rn + BATCH * NN;                         // 16
    float* s1buf = lrbuf + 16;                              // 16

    zero_ws_kernel<<<3, 256, 0, stream>>>(zreg, ZN);
    row_norms_kernel<<<BATCH * 512, 64, 0, stream>>>(nc, ec, nn, en, rc, rn);
    gemm_q_kernel<<<dim3(8, 8, BATCH), 256, 0, stream>>>(nc, ec, nn, en, rc, rn,
                                                         qm, sumq, sumq2);
    init_scalars_kernel<<<1, 64, 0, stream>>>(sumq, sumq2, lrbuf, s1buf);

    void* args[] = { (void*)&qm, (void*)&lrbuf, (void*)&s1buf,
                     (void*)&part, (void*)&flags, (void*)&out };
    hipLaunchCooperativeKernel((const void*)qp_iter_kernel,
                               dim3(NBLK), dim3(1024),
                               args, 0, stream);
}